// Round 10
// baseline (630.732 us; speedup 1.0000x reference)
//
#include <hip/hip_runtime.h>

typedef unsigned short u16;
typedef _Float16 f16x8 __attribute__((ext_vector_type(8)));
typedef short bf16x8 __attribute__((ext_vector_type(8)));
typedef float f32x16 __attribute__((ext_vector_type(16)));
typedef unsigned int u32x4 __attribute__((ext_vector_type(4)));

#define LOG2E 1.44269504088896340736f

static __device__ __forceinline__ u16 f2h(float f){
  union { _Float16 h; u16 u; } v; v.h = (_Float16)f; return v.u;
}
static __device__ __forceinline__ u16 f2bf(float f){
  union { float f; unsigned u; } v; v.f = f;
  return (u16)((v.u + 0x7fffu + ((v.u >> 16) & 1u)) >> 16);
}
static __device__ __forceinline__ unsigned pk2bf(float lo, float hi){
  unsigned r; asm("v_cvt_pk_bf16_f32 %0, %1, %2" : "=v"(r) : "v"(lo), "v"(hi)); return r;
}
static __device__ __forceinline__ float ex2(float x){
#if __has_builtin(__builtin_amdgcn_exp2f)
  return __builtin_amdgcn_exp2f(x);
#else
  return exp2f(x);
#endif
}
#define PSWAP(a, b) asm("v_permlane32_swap_b32 %0, %1" : "+v"(a), "+v"(b))

// B=8, C=512, N=4096, MID=64
// ---------------- kernel 0: x[b][c][n] f32 -> xt[b][n][c] f16 ----------------
__global__ __launch_bounds__(256) void k_tr(const float* __restrict__ x, u16* __restrict__ xt){
  int bx = blockIdx.x;
  int nb = bx & 63, cb = (bx >> 6) & 7, b = bx >> 9;
  __shared__ u16 lt[64 * 68];
  int t = threadIdx.x;
  int cl = t >> 4, n0 = (t & 15) * 4;
  const float* xp = x + ((size_t)(b * 512 + cb * 64)) * 4096 + nb * 64;
#pragma unroll
  for (int i = 0; i < 4; ++i) {
    int c = cl + i * 16;
    float4 v = *(const float4*)(xp + (size_t)c * 4096 + n0);
    u16* d = &lt[c * 68 + n0];
    d[0] = f2h(v.x); d[1] = f2h(v.y); d[2] = f2h(v.z); d[3] = f2h(v.w);
  }
  __syncthreads();
  u16* xo = xt + ((size_t)(b * 4096 + nb * 64)) * 512 + cb * 64;
#pragma unroll
  for (int i = 0; i < 2; ++i) {
    int s = t + i * 256;
    int n = s >> 3, ch = s & 7;
    u32x4 o;
#pragma unroll
    for (int j = 0; j < 4; ++j) {
      u16 a = lt[(ch * 8 + 2 * j) * 68 + n];
      u16 bb = lt[(ch * 8 + 2 * j + 1) * 68 + n];
      o[j] = (unsigned)a | ((unsigned)bb << 16);
    }
    *(u32x4*)(xo + (size_t)n * 512 + ch * 8) = o;
  }
}

// ------------- kernel 1: qk[b][n][0..64)=Q=Xt*(LOG2E*Wb)^T, [64..128)=K=Xt*Wc^T -------------
__global__ __launch_bounds__(512) void k_pqk(const u16* __restrict__ xt, const float* __restrict__ wb,
                                             const float* __restrict__ wc, u16* __restrict__ qk){
  int bx = blockIdx.x;
  int nb = bx & 31, b = bx >> 5;
  __shared__ u16 lx[128 * 64];
  __shared__ u16 lw[128 * 64];
  int t = threadIdx.x, w = t >> 6, l = t & 63, hi = l >> 5, ln = l & 31;
  int wr = w >> 1, wcol = w & 1;
  f32x16 acc[2] = {};
  for (int kt = 0; kt < 8; ++kt) {
    int c0 = kt * 64;
#pragma unroll
    for (int i = 0; i < 2; ++i) {
      int s = t + i * 512; int row = s >> 3, ch = s & 7;
      u32x4 v = *(const u32x4*)(xt + ((size_t)(b * 4096 + nb * 128 + row)) * 512 + c0 + ch * 8);
      *(u32x4*)((char*)lx + ((row * 128 + ch * 16) ^ ((row & 7) << 4))) = v;
    }
#pragma unroll
    for (int i = 0; i < 4; ++i) {
      int s = t + i * 512; int row = s >> 4, c4 = s & 15;
      const float* src = (row < 64) ? (wb + (size_t)row * 512 + c0 + c4 * 4)
                                    : (wc + (size_t)(row - 64) * 512 + c0 + c4 * 4);
      float4 v = *(const float4*)src;
      float sc = (row < 64) ? LOG2E : 1.0f;
      unsigned lo = (unsigned)f2h(v.x * sc) | ((unsigned)f2h(v.y * sc) << 16);
      unsigned h2 = (unsigned)f2h(v.z * sc) | ((unsigned)f2h(v.w * sc) << 16);
      unsigned long long qv = ((unsigned long long)h2 << 32) | lo;
      *(unsigned long long*)((char*)lw + ((row * 128 + c4 * 8) ^ ((row & 7) << 4))) = qv;
    }
    __syncthreads();
#pragma unroll
    for (int cc = 0; cc < 4; ++cc) {
      int ra = wr * 32 + ln;
      f16x8 a = *(const f16x8*)((char*)lx + ((ra * 128 + cc * 32 + hi * 16) ^ ((ra & 7) << 4)));
#pragma unroll
      for (int mt = 0; mt < 2; ++mt) {
        int rb = wcol * 64 + mt * 32 + ln;
        f16x8 bb = *(const f16x8*)((char*)lw + ((rb * 128 + cc * 32 + hi * 16) ^ ((rb & 7) << 4)));
        acc[mt] = __builtin_amdgcn_mfma_f32_32x32x16_f16(a, bb, acc[mt], 0, 0, 0);
      }
    }
    __syncthreads();
  }
#pragma unroll
  for (int mt = 0; mt < 2; ++mt)
#pragma unroll
    for (int r = 0; r < 16; ++r) {
      int n = wr * 32 + (r & 3) + 8 * (r >> 2) + 4 * hi;
      int m = wcol * 64 + mt * 32 + ln;
      qk[((size_t)(b * 4096 + nb * 128 + n)) * 128 + m] = f2h(acc[mt][r]);
    }
}

// ------------- kernel 2: vt[b][o][n] = (Wd * Xt^T), bf16 output -------------
__global__ __launch_bounds__(512) void k_pv(const u16* __restrict__ xt, const float* __restrict__ wd,
                                            u16* __restrict__ vt){
  int bx = blockIdx.x;
  int nb = bx & 31, ob = (bx >> 5) & 3, b = bx >> 7;
  __shared__ u16 lx[128 * 64];
  __shared__ u16 lw[128 * 64];
  int t = threadIdx.x, w = t >> 6, l = t & 63, hi = l >> 5, ln = l & 31;
  int wr = w >> 2, wn = w & 3;
  f32x16 acc[2] = {};
  for (int kt = 0; kt < 8; ++kt) {
    int c0 = kt * 64;
#pragma unroll
    for (int i = 0; i < 2; ++i) {
      int s = t + i * 512; int row = s >> 3, ch = s & 7;
      u32x4 v = *(const u32x4*)(xt + ((size_t)(b * 4096 + nb * 128 + row)) * 512 + c0 + ch * 8);
      *(u32x4*)((char*)lx + ((row * 128 + ch * 16) ^ ((row & 7) << 4))) = v;
    }
#pragma unroll
    for (int i = 0; i < 4; ++i) {
      int s = t + i * 512; int row = s >> 4, c4 = s & 15;
      const float* src = wd + (size_t)(ob * 128 + row) * 512 + c0 + c4 * 4;
      float4 v = *(const float4*)src;
      unsigned lo = (unsigned)f2h(v.x) | ((unsigned)f2h(v.y) << 16);
      unsigned h2 = (unsigned)f2h(v.z) | ((unsigned)f2h(v.w) << 16);
      unsigned long long qv = ((unsigned long long)h2 << 32) | lo;
      *(unsigned long long*)((char*)lw + ((row * 128 + c4 * 8) ^ ((row & 7) << 4))) = qv;
    }
    __syncthreads();
#pragma unroll
    for (int cc = 0; cc < 4; ++cc) {
      int rb = wn * 32 + ln;
      f16x8 bb = *(const f16x8*)((char*)lx + ((rb * 128 + cc * 32 + hi * 16) ^ ((rb & 7) << 4)));
#pragma unroll
      for (int ot = 0; ot < 2; ++ot) {
        int ra = wr * 64 + ot * 32 + ln;
        f16x8 a = *(const f16x8*)((char*)lw + ((ra * 128 + cc * 32 + hi * 16) ^ ((ra & 7) << 4)));
        acc[ot] = __builtin_amdgcn_mfma_f32_32x32x16_f16(a, bb, acc[ot], 0, 0, 0);
      }
    }
    __syncthreads();
  }
#pragma unroll
  for (int ot = 0; ot < 2; ++ot)
#pragma unroll
    for (int r = 0; r < 16; ++r) {
      int o = ob * 128 + wr * 64 + ot * 32 + (r & 3) + 8 * (r >> 2) + 4 * hi;
      int n = nb * 128 + wn * 32 + ln;
      vt[((size_t)(b * 512 + o)) * 4096 + n] = f2bf(acc[ot][r]);
    }
}

// ------------- kernel 3: flash attention; 8 waves x 64 q (q-sub 2); o-chunk 128 -------------
// grid 256 (1 block/CU, b pinned per XCD). P = exp2(S), no max/stats. Reg-staged LDS
// (R8-proven), 2 barriers/iter. V LDS reads feed BOTH q-subs (bytes/MFMA 1.0 -> 0.67 KB).
// Register diet: sequential q-sub QK keeps s-live at 32 (R9 spilled at 64).
__global__ __launch_bounds__(512, 1) void k_attn2(const u16* __restrict__ qk, const u16* __restrict__ vt,
                                                  const float* __restrict__ x, const float* __restrict__ gamma,
                                                  float* __restrict__ out){
  __shared__ char smem[33792];  // lk 8KB @0, lv 16KB @8192; epilogue tb overlays (33792B)
  int bx = blockIdx.x;
  int orig = (bx & 7) * 32 + (bx >> 3);   // XCD-chunked: each XCD owns one batch b
  int b = orig >> 5;
  int qt = (orig >> 2) & 7, oc = orig & 3;
  int obase = oc * 128;
  int t = threadIdx.x, w = t >> 6, l = t & 63, hi = l >> 5, ln = l & 31;
  size_t b4096 = (size_t)b * 4096;
  // Q fragments for both q-subs (log2e folded in k_pqk)
  f16x8 qf0[4], qf1[4];
  {
    const u16* q0 = qk + (b4096 + qt * 512 + w * 64 + ln) * 128;
    const u16* q1 = q0 + 32 * 128;
#pragma unroll
    for (int ch = 0; ch < 4; ++ch) {
      qf0[ch] = *(const f16x8*)(q0 + ch * 16 + hi * 8);
      qf1[ch] = *(const f16x8*)(q1 + ch * 16 + hi * 8);
    }
  }
  // hoisted swizzled offsets
  int rowS = t >> 3, chS = t & 7;
  unsigned wOff = (unsigned)(rowS * 128 + ((chS * 16) ^ ((rowS & 7) << 4)));
  unsigned rb[4];
#pragma unroll
  for (int cc = 0; cc < 4; ++cc)
    rb[cc] = (unsigned)(ln * 128 + (((cc << 5) | (hi << 4)) ^ ((ln & 7) << 4)));
  // global staging pointers (reg staging, R8-proven)
  const u16* gK = qk + (b4096 + rowS) * 128 + 64 + chS * 8;
  const u16* gV0 = vt + ((size_t)(b * 512 + obase + rowS)) * 4096 + chS * 8;
  const u16* gV1 = gV0 + (size_t)64 * 4096;
  u32x4 kreg = *(const u32x4*)gK;
  u32x4 vr0 = *(const u32x4*)gV0, vr1 = *(const u32x4*)gV1;
  f32x16 acc0[4] = {}, acc1[4] = {};
  float lacc0 = 0.0f, lacc1 = 0.0f;
  for (int kt = 0; kt < 64; ++kt) {
    *(u32x4*)(smem + wOff)         = kreg;   // lk
    *(u32x4*)(smem + 8192  + wOff) = vr0;    // lv rows 0-63
    *(u32x4*)(smem + 16384 + wOff) = vr1;    // lv rows 64-127
    __syncthreads();
    if (kt < 63) {  // prefetch next tile into regs (hides under compute)
      gK += 8192; gV0 += 64; gV1 += 64;
      kreg = *(const u32x4*)gK;
      vr0 = *(const u32x4*)gV0; vr1 = *(const u32x4*)gV1;
    }
    union U8 { unsigned u[4]; bf16x8 v; } pa0[4], pa1[4];
    // ---- q-sub 0: QK -> exp2 -> pack (s-live capped at 32) ----
    {
      f32x16 s0 = {}, s1 = {};
      __builtin_amdgcn_s_setprio(1);
#pragma unroll
      for (int cc = 0; cc < 4; ++cc) {
        f16x8 k0 = *(const f16x8*)(smem + rb[cc]);
        f16x8 k1 = *(const f16x8*)(smem + 4096 + rb[cc]);
        s0 = __builtin_amdgcn_mfma_f32_32x32x16_f16(k0, qf0[cc], s0, 0, 0, 0);
        s1 = __builtin_amdgcn_mfma_f32_32x32x16_f16(k1, qf0[cc], s1, 0, 0, 0);
      }
      __builtin_amdgcn_s_setprio(0);
#pragma unroll
      for (int r = 0; r < 16; ++r) s0[r] = ex2(s0[r]);
#pragma unroll
      for (int r = 0; r < 16; ++r) s1[r] = ex2(s1[r]);
      {
        float p[16];
#pragma unroll
        for (int r = 0; r < 16; ++r) p[r] = s0[r] + s1[r];
#pragma unroll
        for (int d = 8; d >= 1; d >>= 1)
#pragma unroll
          for (int r = 0; r < d; ++r) p[r] += p[r + d];
        lacc0 += p[0];
      }
      unsigned c0[8], c1[8];
#pragma unroll
      for (int i = 0; i < 8; ++i) c0[i] = pk2bf(s0[2 * i], s0[2 * i + 1]);
#pragma unroll
      for (int i = 0; i < 8; ++i) c1[i] = pk2bf(s1[2 * i], s1[2 * i + 1]);
      PSWAP(c0[0], c0[2]); PSWAP(c0[1], c0[3]); PSWAP(c0[4], c0[6]); PSWAP(c0[5], c0[7]);
      PSWAP(c1[0], c1[2]); PSWAP(c1[1], c1[3]); PSWAP(c1[4], c1[6]); PSWAP(c1[5], c1[7]);
#pragma unroll
      for (int j = 0; j < 4; ++j) { pa0[0].u[j] = c0[j]; pa0[1].u[j] = c0[4 + j]; pa0[2].u[j] = c1[j]; pa0[3].u[j] = c1[4 + j]; }
    }
    // ---- q-sub 1: QK (K frags re-read) -> exp2 -> pack ----
    {
      f32x16 s0 = {}, s1 = {};
      __builtin_amdgcn_s_setprio(1);
#pragma unroll
      for (int cc = 0; cc < 4; ++cc) {
        f16x8 k0 = *(const f16x8*)(smem + rb[cc]);
        f16x8 k1 = *(const f16x8*)(smem + 4096 + rb[cc]);
        s0 = __builtin_amdgcn_mfma_f32_32x32x16_f16(k0, qf1[cc], s0, 0, 0, 0);
        s1 = __builtin_amdgcn_mfma_f32_32x32x16_f16(k1, qf1[cc], s1, 0, 0, 0);
      }
      __builtin_amdgcn_s_setprio(0);
#pragma unroll
      for (int r = 0; r < 16; ++r) s0[r] = ex2(s0[r]);
#pragma unroll
      for (int r = 0; r < 16; ++r) s1[r] = ex2(s1[r]);
      {
        float p[16];
#pragma unroll
        for (int r = 0; r < 16; ++r) p[r] = s0[r] + s1[r];
#pragma unroll
        for (int d = 8; d >= 1; d >>= 1)
#pragma unroll
          for (int r = 0; r < d; ++r) p[r] += p[r + d];
        lacc1 += p[0];
      }
      unsigned c0[8], c1[8];
#pragma unroll
      for (int i = 0; i < 8; ++i) c0[i] = pk2bf(s0[2 * i], s0[2 * i + 1]);
#pragma unroll
      for (int i = 0; i < 8; ++i) c1[i] = pk2bf(s1[2 * i], s1[2 * i + 1]);
      PSWAP(c0[0], c0[2]); PSWAP(c0[1], c0[3]); PSWAP(c0[4], c0[6]); PSWAP(c0[5], c0[7]);
      PSWAP(c1[0], c1[2]); PSWAP(c1[1], c1[3]); PSWAP(c1[4], c1[6]); PSWAP(c1[5], c1[7]);
#pragma unroll
      for (int j = 0; j < 4; ++j) { pa1[0].u[j] = c0[j]; pa1[1].u[j] = c0[4 + j]; pa1[2].u[j] = c1[j]; pa1[3].u[j] = c1[4 + j]; }
    }
    // ---- PV: each vb read feeds both q-subs ----
    __builtin_amdgcn_s_setprio(1);
#pragma unroll
    for (int kc = 0; kc < 4; ++kc) {
#pragma unroll
      for (int ot = 0; ot < 4; ++ot) {
        bf16x8 vb = *(const bf16x8*)(smem + 8192 + ot * 4096 + rb[kc]);
        acc0[ot] = __builtin_amdgcn_mfma_f32_32x32x16_bf16(pa0[kc].v, vb, acc0[ot], 0, 0, 0);
        acc1[ot] = __builtin_amdgcn_mfma_f32_32x32x16_bf16(pa1[kc].v, vb, acc1[ot], 0, 0, 0);
      }
    }
    __builtin_amdgcn_s_setprio(0);
    __syncthreads();
  }
  // epilogue: per-q scale gamma/l; transpose 32x32 tiles via per-wave LDS; coalesced store
  float g = gamma[0];
  float l0 = lacc0 + __shfl_xor(lacc0, 32);
  float l1 = lacc1 + __shfl_xor(lacc1, 32);
  float sinv0 = g / l0, sinv1 = g / l1;
  __syncthreads();
  float* tb = (float*)smem + w * 1056;  // 32x33 f32 per wave
#pragma unroll
  for (int qs = 0; qs < 2; ++qs) {
    float sv = qs ? sinv1 : sinv0;
    size_t qcol = (size_t)(qt * 512 + w * 64 + qs * 32 + ln);
#pragma unroll
    for (int ot = 0; ot < 4; ++ot) {
      f32x16& av = qs ? acc1[ot] : acc0[ot];
#pragma unroll
      for (int r = 0; r < 16; ++r) {
        int qr = (r & 3) + 8 * (r >> 2) + 4 * hi;
        tb[ln * 33 + qr] = av[r];
      }
#pragma unroll
      for (int it = 0; it < 16; ++it) {
        int orow = it * 2 + hi;
        float v = tb[orow * 33 + ln];
        size_t gi = (((size_t)(b * 512 + obase + ot * 32 + orow)) << 12) + qcol;
        out[gi] = sv * v + x[gi];
      }
      __syncthreads();
    }
  }
}

extern "C" void kernel_launch(void* const* d_in, const int* in_sizes, int n_in,
                              void* d_out, int out_size, void* d_ws, size_t ws_size,
                              hipStream_t stream) {
  (void)in_sizes; (void)n_in; (void)out_size; (void)ws_size;
  const float* x     = (const float*)d_in[0];
  const float* wb    = (const float*)d_in[1];
  const float* wc    = (const float*)d_in[2];
  const float* wd    = (const float*)d_in[3];
  const float* gamma = (const float*)d_in[4];
  float* out = (float*)d_out;
  char* ws = (char*)d_ws;
  u16* xt  = (u16*)ws;                    // 32 MB: Xt f16 [B][N][C]
  u16* qkb = (u16*)(ws + 33554432);       //  8 MB: [B][N][Q(64)|K(64)] f16
  u16* vtb = (u16*)(ws + 41943040);       // 32 MB: V^T bf16 [B][C][N]
  k_tr   <<<dim3(4096), dim3(256), 0, stream>>>(x, xt);
  k_pqk  <<<dim3(256),  dim3(512), 0, stream>>>(xt, wb, wc, qkb);
  k_pv   <<<dim3(1024), dim3(512), 0, stream>>>(xt, wd, vtb);
  k_attn2<<<dim3(256),  dim3(512), 0, stream>>>(qkb, vtb, x, gamma, out);
}

// Round 11
// 249.915 us; speedup vs baseline: 2.5238x; 2.5238x over previous
//
#include <hip/hip_runtime.h>

typedef unsigned short u16;
typedef _Float16 f16x8 __attribute__((ext_vector_type(8)));
typedef short bf16x8 __attribute__((ext_vector_type(8)));
typedef float f32x16 __attribute__((ext_vector_type(16)));
typedef unsigned int u32x4 __attribute__((ext_vector_type(4)));

#define LOG2E 1.44269504088896340736f

static __device__ __forceinline__ u16 f2h(float f){
  union { _Float16 h; u16 u; } v; v.h = (_Float16)f; return v.u;
}
static __device__ __forceinline__ u16 f2bf(float f){
  union { float f; unsigned u; } v; v.f = f;
  return (u16)((v.u + 0x7fffu + ((v.u >> 16) & 1u)) >> 16);
}
static __device__ __forceinline__ unsigned pk2bf(float lo, float hi){
  unsigned r; asm("v_cvt_pk_bf16_f32 %0, %1, %2" : "=v"(r) : "v"(lo), "v"(hi)); return r;
}
static __device__ __forceinline__ float ex2(float x){
#if __has_builtin(__builtin_amdgcn_exp2f)
  return __builtin_amdgcn_exp2f(x);
#else
  return exp2f(x);
#endif
}
#define PSWAP(a, b) asm("v_permlane32_swap_b32 %0, %1" : "+v"(a), "+v"(b))

// B=8, C=512, N=4096, MID=64
// ---------------- kernel 0: x[b][c][n] f32 -> xt[b][n][c] f16 ----------------
__global__ __launch_bounds__(256) void k_tr(const float* __restrict__ x, u16* __restrict__ xt){
  int bx = blockIdx.x;
  int nb = bx & 63, cb = (bx >> 6) & 7, b = bx >> 9;
  __shared__ u16 lt[64 * 68];
  int t = threadIdx.x;
  int cl = t >> 4, n0 = (t & 15) * 4;
  const float* xp = x + ((size_t)(b * 512 + cb * 64)) * 4096 + nb * 64;
#pragma unroll
  for (int i = 0; i < 4; ++i) {
    int c = cl + i * 16;
    float4 v = *(const float4*)(xp + (size_t)c * 4096 + n0);
    u16* d = &lt[c * 68 + n0];
    d[0] = f2h(v.x); d[1] = f2h(v.y); d[2] = f2h(v.z); d[3] = f2h(v.w);
  }
  __syncthreads();
  u16* xo = xt + ((size_t)(b * 4096 + nb * 64)) * 512 + cb * 64;
#pragma unroll
  for (int i = 0; i < 2; ++i) {
    int s = t + i * 256;
    int n = s >> 3, ch = s & 7;
    u32x4 o;
#pragma unroll
    for (int j = 0; j < 4; ++j) {
      u16 a = lt[(ch * 8 + 2 * j) * 68 + n];
      u16 bb = lt[(ch * 8 + 2 * j + 1) * 68 + n];
      o[j] = (unsigned)a | ((unsigned)bb << 16);
    }
    *(u32x4*)(xo + (size_t)n * 512 + ch * 8) = o;
  }
}

// ------------- kernel 1: qk[b][n][0..64)=Q=Xt*(LOG2E*Wb)^T, [64..128)=K=Xt*Wc^T -------------
__global__ __launch_bounds__(512) void k_pqk(const u16* __restrict__ xt, const float* __restrict__ wb,
                                             const float* __restrict__ wc, u16* __restrict__ qk){
  int bx = blockIdx.x;
  int nb = bx & 31, b = bx >> 5;
  __shared__ u16 lx[128 * 64];
  __shared__ u16 lw[128 * 64];
  int t = threadIdx.x, w = t >> 6, l = t & 63, hi = l >> 5, ln = l & 31;
  int wr = w >> 1, wcol = w & 1;
  f32x16 acc[2] = {};
  for (int kt = 0; kt < 8; ++kt) {
    int c0 = kt * 64;
#pragma unroll
    for (int i = 0; i < 2; ++i) {
      int s = t + i * 512; int row = s >> 3, ch = s & 7;
      u32x4 v = *(const u32x4*)(xt + ((size_t)(b * 4096 + nb * 128 + row)) * 512 + c0 + ch * 8);
      *(u32x4*)((char*)lx + ((row * 128 + ch * 16) ^ ((row & 7) << 4))) = v;
    }
#pragma unroll
    for (int i = 0; i < 4; ++i) {
      int s = t + i * 512; int row = s >> 4, c4 = s & 15;
      const float* src = (row < 64) ? (wb + (size_t)row * 512 + c0 + c4 * 4)
                                    : (wc + (size_t)(row - 64) * 512 + c0 + c4 * 4);
      float4 v = *(const float4*)src;
      float sc = (row < 64) ? LOG2E : 1.0f;
      unsigned lo = (unsigned)f2h(v.x * sc) | ((unsigned)f2h(v.y * sc) << 16);
      unsigned h2 = (unsigned)f2h(v.z * sc) | ((unsigned)f2h(v.w * sc) << 16);
      unsigned long long qv = ((unsigned long long)h2 << 32) | lo;
      *(unsigned long long*)((char*)lw + ((row * 128 + c4 * 8) ^ ((row & 7) << 4))) = qv;
    }
    __syncthreads();
#pragma unroll
    for (int cc = 0; cc < 4; ++cc) {
      int ra = wr * 32 + ln;
      f16x8 a = *(const f16x8*)((char*)lx + ((ra * 128 + cc * 32 + hi * 16) ^ ((ra & 7) << 4)));
#pragma unroll
      for (int mt = 0; mt < 2; ++mt) {
        int rb = wcol * 64 + mt * 32 + ln;
        f16x8 bb = *(const f16x8*)((char*)lw + ((rb * 128 + cc * 32 + hi * 16) ^ ((rb & 7) << 4)));
        acc[mt] = __builtin_amdgcn_mfma_f32_32x32x16_f16(a, bb, acc[mt], 0, 0, 0);
      }
    }
    __syncthreads();
  }
#pragma unroll
  for (int mt = 0; mt < 2; ++mt)
#pragma unroll
    for (int r = 0; r < 16; ++r) {
      int n = wr * 32 + (r & 3) + 8 * (r >> 2) + 4 * hi;
      int m = wcol * 64 + mt * 32 + ln;
      qk[((size_t)(b * 4096 + nb * 128 + n)) * 128 + m] = f2h(acc[mt][r]);
    }
}

// ------------- kernel 2: vt[b][o][n] = (Wd * Xt^T), bf16 output -------------
__global__ __launch_bounds__(512) void k_pv(const u16* __restrict__ xt, const float* __restrict__ wd,
                                            u16* __restrict__ vt){
  int bx = blockIdx.x;
  int nb = bx & 31, ob = (bx >> 5) & 3, b = bx >> 7;
  __shared__ u16 lx[128 * 64];
  __shared__ u16 lw[128 * 64];
  int t = threadIdx.x, w = t >> 6, l = t & 63, hi = l >> 5, ln = l & 31;
  int wr = w >> 2, wn = w & 3;
  f32x16 acc[2] = {};
  for (int kt = 0; kt < 8; ++kt) {
    int c0 = kt * 64;
#pragma unroll
    for (int i = 0; i < 2; ++i) {
      int s = t + i * 512; int row = s >> 3, ch = s & 7;
      u32x4 v = *(const u32x4*)(xt + ((size_t)(b * 4096 + nb * 128 + row)) * 512 + c0 + ch * 8);
      *(u32x4*)((char*)lx + ((row * 128 + ch * 16) ^ ((row & 7) << 4))) = v;
    }
#pragma unroll
    for (int i = 0; i < 4; ++i) {
      int s = t + i * 512; int row = s >> 4, c4 = s & 15;
      const float* src = wd + (size_t)(ob * 128 + row) * 512 + c0 + c4 * 4;
      float4 v = *(const float4*)src;
      unsigned lo = (unsigned)f2h(v.x) | ((unsigned)f2h(v.y) << 16);
      unsigned h2 = (unsigned)f2h(v.z) | ((unsigned)f2h(v.w) << 16);
      unsigned long long qv = ((unsigned long long)h2 << 32) | lo;
      *(unsigned long long*)((char*)lw + ((row * 128 + c4 * 8) ^ ((row & 7) << 4))) = qv;
    }
    __syncthreads();
#pragma unroll
    for (int cc = 0; cc < 4; ++cc) {
      int rb = wn * 32 + ln;
      f16x8 bb = *(const f16x8*)((char*)lx + ((rb * 128 + cc * 32 + hi * 16) ^ ((rb & 7) << 4)));
#pragma unroll
      for (int ot = 0; ot < 2; ++ot) {
        int ra = wr * 64 + ot * 32 + ln;
        f16x8 a = *(const f16x8*)((char*)lw + ((ra * 128 + cc * 32 + hi * 16) ^ ((ra & 7) << 4)));
        acc[ot] = __builtin_amdgcn_mfma_f32_32x32x16_f16(a, bb, acc[ot], 0, 0, 0);
      }
    }
    __syncthreads();
  }
#pragma unroll
  for (int ot = 0; ot < 2; ++ot)
#pragma unroll
    for (int r = 0; r < 16; ++r) {
      int o = ob * 128 + wr * 64 + ot * 32 + (r & 3) + 8 * (r >> 2) + 4 * hi;
      int n = nb * 128 + wn * 32 + ln;
      vt[((size_t)(b * 512 + o)) * 4096 + n] = f2bf(acc[ot][r]);
    }
}

// ------------- kernel 3: flash attention, o-chunk 256 (R8 structure + LDS double-buffer) -------------
// P = exp2(S) directly, no max/stats. grid 256 XCD-chunked. 8 waves x 32 q; KV tile 64.
// Double buffer (2 x 40 KB): ONE barrier per iter; staging writes overlap other waves' compute.
__global__ __launch_bounds__(512, 1) void k_attn2(const u16* __restrict__ qk, const u16* __restrict__ vt,
                                                  const float* __restrict__ x, const float* __restrict__ gamma,
                                                  float* __restrict__ out){
  __shared__ char smem[81920];   // buf[i] at i*40960: lk 8KB @+0, lv 32KB @+8192
  int bx = blockIdx.x;
  int orig = (bx & 7) * 32 + (bx >> 3);
  int combo = orig >> 4, qt = orig & 15;
  int b = combo >> 1, oc2 = combo & 1;
  int obase = oc2 * 256;
  int t = threadIdx.x, w = t >> 6, l = t & 63, hi = l >> 5, ln = l & 31;
  int q = qt * 256 + w * 32 + ln;
  size_t b4096 = (size_t)b * 4096;
  // Q B-fragments (log2e folded in k_pqk)
  f16x8 qf[4];
  {
    const u16* qrow = qk + (b4096 + q) * 128;
#pragma unroll
    for (int ch = 0; ch < 4; ++ch) qf[ch] = *(const f16x8*)(qrow + ch * 16 + hi * 8);
  }
  // hoisted LDS addressing
  int rowS = t >> 3, chS = t & 7;
  unsigned wOff = (unsigned)(rowS * 128 + ((chS * 16) ^ ((rowS & 7) << 4)));
  unsigned rb[4];
#pragma unroll
  for (int cc = 0; cc < 4; ++cc)
    rb[cc] = (unsigned)(ln * 128 + (((cc << 5) | (hi << 4)) ^ ((ln & 7) << 4)));
  // global staging pointers
  const u16* gK = qk + (b4096 + rowS) * 128 + 64 + chS * 8;
  const u16* gV0 = vt + ((size_t)(b * 512 + obase + rowS)) * 4096 + chS * 8;
  const u16* gV1 = gV0 + (size_t)64 * 4096;
  const u16* gV2 = gV0 + (size_t)128 * 4096;
  const u16* gV3 = gV0 + (size_t)192 * 4096;
  u32x4 kreg = *(const u32x4*)gK;
  u32x4 vr0 = *(const u32x4*)gV0, vr1 = *(const u32x4*)gV1;
  u32x4 vr2 = *(const u32x4*)gV2, vr3 = *(const u32x4*)gV3;
  // prologue: write tile 0 into buf0
  *(u32x4*)(smem + wOff)         = kreg;
  *(u32x4*)(smem + 8192  + wOff) = vr0;
  *(u32x4*)(smem + 16384 + wOff) = vr1;
  *(u32x4*)(smem + 24576 + wOff) = vr2;
  *(u32x4*)(smem + 32768 + wOff) = vr3;
  gK += 8192; gV0 += 64; gV1 += 64; gV2 += 64; gV3 += 64;
  f32x16 acc[8] = {};
  float lacc = 0.0f;
  for (int kt = 0; kt < 64; ++kt) {
    __syncthreads();   // buf[kt&1] writes visible; prior reads of buf[(kt+1)&1] complete
    char* bufp = smem + (kt & 1) * 40960;
    char* bufn = smem + ((kt + 1) & 1) * 40960;
    if (kt < 63) {     // issue next-tile loads now; latency hides under this iter's compute
      kreg = *(const u32x4*)gK;
      vr0 = *(const u32x4*)gV0; vr1 = *(const u32x4*)gV1;
      vr2 = *(const u32x4*)gV2; vr3 = *(const u32x4*)gV3;
      gK += 8192; gV0 += 64; gV1 += 64; gV2 += 64; gV3 += 64;
    }
    // S^T = K * Q^T : lane holds 32 scores for q=ln (hi splits k 0-31 / 32-63)
    f32x16 s0 = {}, s1 = {};
    __builtin_amdgcn_s_setprio(1);
#pragma unroll
    for (int cc = 0; cc < 4; ++cc) {
      f16x8 k0 = *(const f16x8*)(bufp + rb[cc]);
      f16x8 k1 = *(const f16x8*)(bufp + 4096 + rb[cc]);
      s0 = __builtin_amdgcn_mfma_f32_32x32x16_f16(k0, qf[cc], s0, 0, 0, 0);
      s1 = __builtin_amdgcn_mfma_f32_32x32x16_f16(k1, qf[cc], s1, 0, 0, 0);
    }
    __builtin_amdgcn_s_setprio(0);
    // P = exp2(S) (no max), tree row-sum
#pragma unroll
    for (int r = 0; r < 16; ++r) s0[r] = ex2(s0[r]);
#pragma unroll
    for (int r = 0; r < 16; ++r) s1[r] = ex2(s1[r]);
    {
      float p[16];
#pragma unroll
      for (int r = 0; r < 16; ++r) p[r] = s0[r] + s1[r];
#pragma unroll
      for (int d = 8; d >= 1; d >>= 1)
#pragma unroll
        for (int r = 0; r < d; ++r) p[r] += p[r + d];
      lacc += p[0];
    }
    // pack P -> bf16 A-fragments via cvt_pk + permlane32_swap
    unsigned c0[8], c1[8];
#pragma unroll
    for (int i = 0; i < 8; ++i) c0[i] = pk2bf(s0[2 * i], s0[2 * i + 1]);
#pragma unroll
    for (int i = 0; i < 8; ++i) c1[i] = pk2bf(s1[2 * i], s1[2 * i + 1]);
    PSWAP(c0[0], c0[2]); PSWAP(c0[1], c0[3]); PSWAP(c0[4], c0[6]); PSWAP(c0[5], c0[7]);
    PSWAP(c1[0], c1[2]); PSWAP(c1[1], c1[3]); PSWAP(c1[4], c1[6]); PSWAP(c1[5], c1[7]);
    union U8 { unsigned u[4]; bf16x8 v; } pa[4];
#pragma unroll
    for (int j = 0; j < 4; ++j) { pa[0].u[j] = c0[j]; pa[1].u[j] = c0[4 + j]; pa[2].u[j] = c1[j]; pa[3].u[j] = c1[4 + j]; }
    // PV
    __builtin_amdgcn_s_setprio(1);
#pragma unroll
    for (int kc = 0; kc < 4; ++kc) {
#pragma unroll
      for (int ot = 0; ot < 8; ++ot) {
        bf16x8 vb = *(const bf16x8*)(bufp + 8192 + ot * 4096 + rb[kc]);
        acc[ot] = __builtin_amdgcn_mfma_f32_32x32x16_bf16(pa[kc].v, vb, acc[ot], 0, 0, 0);
      }
    }
    __builtin_amdgcn_s_setprio(0);
    // tail: write next tile into the other buffer (overlaps other waves' compute)
    if (kt < 63) {
      *(u32x4*)(bufn + wOff)         = kreg;
      *(u32x4*)(bufn + 8192  + wOff) = vr0;
      *(u32x4*)(bufn + 16384 + wOff) = vr1;
      *(u32x4*)(bufn + 24576 + wOff) = vr2;
      *(u32x4*)(bufn + 32768 + wOff) = vr3;
    }
  }
  // epilogue: l per q-row, scale = gamma/l; transpose 32x32 tiles via per-wave LDS; coalesced store
  float l_tot = lacc + __shfl_xor(lacc, 32);
  float sinv = gamma[0] / l_tot;
  __syncthreads();
  float* tb = (float*)smem + w * 1056;  // per-wave 32x33 f32 (overlays buf0; last tile was buf1)
#pragma unroll
  for (int ot = 0; ot < 8; ++ot) {
#pragma unroll
    for (int r = 0; r < 16; ++r) {
      int qr = (r & 3) + 8 * (r >> 2) + 4 * hi;
      tb[ln * 33 + qr] = acc[ot][r];
    }
#pragma unroll
    for (int it = 0; it < 16; ++it) {
      int orow = it * 2 + hi;
      float v = tb[orow * 33 + ln];
      size_t gi = (((size_t)(b * 512 + obase + ot * 32 + orow)) << 12) + (size_t)(qt * 256 + w * 32 + ln);
      out[gi] = sinv * v + x[gi];
    }
  }
}

extern "C" void kernel_launch(void* const* d_in, const int* in_sizes, int n_in,
                              void* d_out, int out_size, void* d_ws, size_t ws_size,
                              hipStream_t stream) {
  (void)in_sizes; (void)n_in; (void)out_size; (void)ws_size;
  const float* x     = (const float*)d_in[0];
  const float* wb    = (const float*)d_in[1];
  const float* wc    = (const float*)d_in[2];
  const float* wd    = (const float*)d_in[3];
  const float* gamma = (const float*)d_in[4];
  float* out = (float*)d_out;
  char* ws = (char*)d_ws;
  u16* xt  = (u16*)ws;                    // 32 MB: Xt f16 [B][N][C]
  u16* qkb = (u16*)(ws + 33554432);       //  8 MB: [B][N][Q(64)|K(64)] f16
  u16* vtb = (u16*)(ws + 41943040);       // 32 MB: V^T bf16 [B][C][N]
  k_tr   <<<dim3(4096), dim3(256), 0, stream>>>(x, xt);
  k_pqk  <<<dim3(256),  dim3(512), 0, stream>>>(xt, wb, wc, qkb);
  k_pv   <<<dim3(1024), dim3(512), 0, stream>>>(xt, wd, vtb);
  k_attn2<<<dim3(256),  dim3(512), 0, stream>>>(qkb, vtb, x, gamma, out);
}